// Round 8
// baseline (742.032 us; speedup 1.0000x reference)
//
#include <hip/hip_runtime.h>

// ---------------------------------------------------------------------------
// PiNet: 2x GCNConv + a2^T a2 readout + linear + softmax
// N=100000, E=3200000, D0=128, D1=D2=64, OUT=10
// R7 == R5/R6 resubmit (two GPUAcquisitionTimeouts; kernel never ran):
//     nt (non-temporal) loads on all edge-list streams so the XCD-sliced
//     scatter's L2 window isn't thrashed by the stream (R4: WRITE 173MB from
//     repeated partial-line evictions). dinv pre-scaled into gemm epilogue:
//     H' = dinv*(XW); agg drops the per-edge dinv[src] gather.
// ---------------------------------------------------------------------------

#define SCAN_B 1024

__global__ void hist_dst(const int* __restrict__ dst, int* __restrict__ counts, int E) {
    int e = blockIdx.x * blockDim.x + threadIdx.x;
    if (e < E) atomicAdd(&counts[__builtin_nontemporal_load(&dst[e])], 1);
}

// exclusive scan, level A: per-block scan of counts -> rowptr, block totals -> bsums
__global__ void scanA(const int* __restrict__ counts, int* __restrict__ rowptr,
                      int* __restrict__ bsums, int N) {
    __shared__ int sh[SCAN_B];
    const int tid = threadIdx.x;
    const int i   = blockIdx.x * SCAN_B + tid;
    int c = (i < N) ? counts[i] : 0;
    sh[tid] = c;
    __syncthreads();
    for (int off = 1; off < SCAN_B; off <<= 1) {
        int t = (tid >= off) ? sh[tid - off] : 0;
        __syncthreads();
        sh[tid] += t;
        __syncthreads();
    }
    if (i < N) rowptr[i] = sh[tid] - c;  // exclusive
    if (tid == SCAN_B - 1) bsums[blockIdx.x] = sh[tid];
}

// level B: exclusive scan of block sums (nb <= 1024), single block
__global__ void scanB(int* __restrict__ bsums, int nb) {
    __shared__ int sh[SCAN_B];
    const int tid = threadIdx.x;
    if (tid < nb) sh[tid] = bsums[tid];
    __syncthreads();
    if (tid == 0) {
        int run = 0;
        for (int k = 0; k < nb; ++k) { int v = sh[k]; sh[k] = run; run += v; }
    }
    __syncthreads();
    if (tid < nb) bsums[tid] = sh[tid];
}

// level C: add block offsets; init cursor = rowptr; dinv = rsqrt(deg+1)
__global__ void scanC(int* __restrict__ rowptr, const int* __restrict__ bsums,
                      const int* __restrict__ counts, int* __restrict__ cursor,
                      float* __restrict__ dinv, int N) {
    int i = blockIdx.x * blockDim.x + threadIdx.x;
    if (i < N) {
        int rp = rowptr[i] + bsums[i >> 10];
        rowptr[i] = rp;
        cursor[i] = rp;
        dinv[i]   = rsqrtf((float)counts[i] + 1.0f);  // +1 self-loop
    }
}

// XCD-sliced scatter: group g = blockIdx%8 handles dst in [g*slice,(g+1)*slice).
// nt loads keep the 51MB edge stream out of L2 so the slice's 1.6MB ssorted
// window and cursor lines stay resident (write amp ~1x).
__global__ __launch_bounds__(256) void xcd_scatter(const int* __restrict__ src,
                                                   const int* __restrict__ dst,
                                                   int* __restrict__ cursor,
                                                   int* __restrict__ ssorted,
                                                   int E, int slice) {
    const int g   = blockIdx.x & 7;
    const int lo  = g * slice;
    const int hi  = lo + slice;
    const int bg  = blockIdx.x >> 3;
    const int nbg = gridDim.x >> 3;
    const int stride = nbg * 256;
    for (int e = bg * 256 + threadIdx.x; e < E; e += stride) {
        int d = __builtin_nontemporal_load(&dst[e]);
        if (d >= lo && d < hi) {
            int s   = __builtin_nontemporal_load(&src[e]);
            int pos = atomicAdd(&cursor[d], 1);
            ssorted[pos] = s;
        }
    }
}

// ---------------------------------------------------------------------------
// Register-tiled GEMM with dinv epilogue: H[n][c] = dinv[n] * sum_k A[n][k]*W[k][c]
// 64 nodes x 64 cols per 256-thread block; each thread computes 4 nodes x 4 cols.
// ---------------------------------------------------------------------------
template <int K>
__global__ __launch_bounds__(256) void gemm_tiled(const float* __restrict__ A,
                                                  const float* __restrict__ W,
                                                  const float* __restrict__ dinv,
                                                  float* __restrict__ H, int N) {
    constexpr int KC = 32;
    __shared__ float xs[64][KC + 4];
    __shared__ float ws[KC][64];
    const int tid  = threadIdx.x;
    const int tx   = tid & 15;
    const int ty   = tid >> 4;
    const int base = blockIdx.x * 64;

    float acc[4][4] = {{0.f}};

    for (int kc = 0; kc < K; kc += KC) {
        for (int idx = tid; idx < 512; idx += 256) {
            int node = idx >> 3, k4 = idx & 7;
            int n = base + node;
            float4 v = make_float4(0.f, 0.f, 0.f, 0.f);
            if (n < N) v = *(const float4*)&A[(long long)n * K + kc + k4 * 4];
            *(float4*)&xs[node][k4 * 4] = v;
        }
        for (int idx = tid; idx < 512; idx += 256) {
            int k = idx >> 4, c4 = idx & 15;
            *(float4*)&ws[k][c4 * 4] = *(const float4*)&W[(long long)(kc + k) * 64 + c4 * 4];
        }
        __syncthreads();

#pragma unroll
        for (int k = 0; k < KC; k += 4) {
            float4 xv[4], wv[4];
#pragma unroll
            for (int i = 0; i < 4; ++i) xv[i] = *(const float4*)&xs[ty * 4 + i][k];
#pragma unroll
            for (int j = 0; j < 4; ++j) wv[j] = *(const float4*)&ws[k + j][tx * 4];
#pragma unroll
            for (int i = 0; i < 4; ++i) {
                float xi[4] = {xv[i].x, xv[i].y, xv[i].z, xv[i].w};
#pragma unroll
                for (int j = 0; j < 4; ++j) {
                    acc[i][0] += xi[j] * wv[j].x;
                    acc[i][1] += xi[j] * wv[j].y;
                    acc[i][2] += xi[j] * wv[j].z;
                    acc[i][3] += xi[j] * wv[j].w;
                }
            }
        }
        __syncthreads();
    }

#pragma unroll
    for (int i = 0; i < 4; ++i) {
        int n = base + ty * 4 + i;
        if (n < N) {
            float d = dinv[n];
            float4 r = make_float4(d * acc[i][0], d * acc[i][1], d * acc[i][2], d * acc[i][3]);
            *(float4*)&H[(long long)n * 64 + tx * 4] = r;
        }
    }
}

// CSR aggregation, fused bias + self-loop. One wave per node.
// H is pre-scaled by dinv: out[n] = bias + dinv[n] * (H[n] + sum_s H[s]).
__global__ void agg_csr(const int* __restrict__ rowptr, const int* __restrict__ endptr,
                        const int* __restrict__ ssorted, const float* __restrict__ dinv,
                        const float* __restrict__ H, const float* __restrict__ bias,
                        float* __restrict__ out, int N) {
    const int wid  = (int)(((long long)blockIdx.x * blockDim.x + threadIdx.x) >> 6);
    if (wid >= N) return;
    const int lane = threadIdx.x & 63;
    const int g    = lane >> 4;
    const int fl   = lane & 15;
    const float4* __restrict__ Hv = (const float4*)H;

    const int   n   = wid;
    const int   beg = rowptr[n];
    const int   end = endptr[n];

    float4 acc = make_float4(0.f, 0.f, 0.f, 0.f);
    for (int e = beg + g; e < end; e += 4) {
        int    s  = __builtin_nontemporal_load(&ssorted[e]);
        float4 hv = Hv[(long long)s * 16 + fl];
        acc.x += hv.x; acc.y += hv.y; acc.z += hv.z; acc.w += hv.w;
    }
    acc.x += __shfl_xor(acc.x, 16); acc.y += __shfl_xor(acc.y, 16);
    acc.z += __shfl_xor(acc.z, 16); acc.w += __shfl_xor(acc.w, 16);
    acc.x += __shfl_xor(acc.x, 32); acc.y += __shfl_xor(acc.y, 32);
    acc.z += __shfl_xor(acc.z, 32); acc.w += __shfl_xor(acc.w, 32);

    if (g == 0) {
        float4 selfv = Hv[(long long)n * 16 + fl];
        float4 bv    = ((const float4*)bias)[fl];
        float  dn    = dinv[n];
        float4 res;
        res.x = bv.x + dn * (selfv.x + acc.x);
        res.y = bv.y + dn * (selfv.y + acc.y);
        res.z = bv.z + dn * (selfv.z + acc.z);
        res.w = bv.w + dn * (selfv.w + acc.w);
        ((float4*)out)[(long long)n * 16 + fl] = res;
    }
}

// h64[r][c] += sum_n A2[n][r] * A2[n][c]
__global__ void outer_reduce(const float* __restrict__ A2, float* __restrict__ h64, int N) {
    __shared__ float rows[8][64];
    const int tid = threadIdx.x;
    const int col = tid & 63;
    const int rg  = tid >> 6;
    float acc[16];
#pragma unroll
    for (int i = 0; i < 16; ++i) acc[i] = 0.f;

    int npb   = (N + gridDim.x - 1) / gridDim.x;
    int start = blockIdx.x * npb;
    int end   = min(start + npb, N);
    for (int nb = start; nb < end; nb += 8) {
        int cnt = min(8, end - nb);
        __syncthreads();
        for (int idx = tid; idx < cnt * 64; idx += 256)
            rows[idx >> 6][idx & 63] = A2[(long long)(nb + (idx >> 6)) * 64 + (idx & 63)];
        __syncthreads();
        for (int r = 0; r < cnt; ++r) {
            float vc = rows[r][col];
#pragma unroll
            for (int i = 0; i < 16; ++i)
                acc[i] += rows[r][rg * 16 + i] * vc;
        }
    }
#pragma unroll
    for (int i = 0; i < 16; ++i)
        atomicAdd(&h64[(rg * 16 + i) * 64 + col], acc[i]);
}

// o = h64.flat @ Wl + bl ; softmax -> out[10]
__global__ void final_kernel(const float* __restrict__ h64, const float* __restrict__ Wl,
                             const float* __restrict__ bl, float* __restrict__ out) {
    __shared__ float red[256];
    __shared__ float o[10];
    const int tid = threadIdx.x;
    float acc[10];
#pragma unroll
    for (int k = 0; k < 10; ++k) acc[k] = 0.f;
    for (int i = tid; i < 4096; i += 256) {
        float v = h64[i];
#pragma unroll
        for (int k = 0; k < 10; ++k) acc[k] += v * Wl[i * 10 + k];
    }
    for (int k = 0; k < 10; ++k) {
        red[tid] = acc[k];
        __syncthreads();
        for (int s = 128; s > 0; s >>= 1) {
            if (tid < s) red[tid] += red[tid + s];
            __syncthreads();
        }
        if (tid == 0) o[k] = red[0] + bl[k];
        __syncthreads();
    }
    if (tid == 0) {
        float m = o[0];
        for (int k = 1; k < 10; ++k) m = fmaxf(m, o[k]);
        float s = 0.f, e[10];
        for (int k = 0; k < 10; ++k) { e[k] = expf(o[k] - m); s += e[k]; }
        for (int k = 0; k < 10; ++k) out[k] = e[k] / s;
    }
}

extern "C" void kernel_launch(void* const* d_in, const int* in_sizes, int n_in,
                              void* d_out, int out_size, void* d_ws, size_t ws_size,
                              hipStream_t stream) {
    const float* x   = (const float*)d_in[0];
    const int*   ei  = (const int*)d_in[1];
    const float* Wa1 = (const float*)d_in[2];
    const float* ba1 = (const float*)d_in[3];
    const float* Wa2 = (const float*)d_in[4];
    const float* ba2 = (const float*)d_in[5];
    const float* Wl  = (const float*)d_in[6];
    const float* bl  = (const float*)d_in[7];
    float* out = (float*)d_out;

    const int N = in_sizes[0] / 128;
    const int E = in_sizes[1] / 2;
    const int* src = ei;
    const int* dst = ei + E;
    const int slice = (N + 7) / 8;

    char* wsb = (char*)d_ws;
    float* bufH   = (float*)wsb;                       wsb += (size_t)N * 64 * 4;
    float* bufA   = (float*)wsb;                       wsb += (size_t)N * 64 * 4;
    float* dinv   = (float*)wsb;                       wsb += (size_t)N * 4;
    float* h64    = (float*)wsb;                       wsb += 4096 * 4;
    int*   counts = (int*)wsb;                         wsb += (size_t)N * 4;
    int*   rowptr = (int*)wsb;                         wsb += (size_t)N * 4;
    int*   cursor = (int*)wsb;                         wsb += (size_t)N * 4;
    int*   bsums  = (int*)wsb;                         wsb += 1024 * 4;
    int*   ssorted= (int*)wsb;                         wsb += (size_t)E * 4;

    const int gN = (N + 255) / 256;
    const int gE = (E + 255) / 256;
    const int nb = (N + SCAN_B - 1) / SCAN_B;

    // --- CSR build ---
    hipMemsetAsync(counts, 0, (size_t)N * 4, stream);
    hist_dst<<<gE, 256, 0, stream>>>(dst, counts, E);
    scanA<<<nb, SCAN_B, 0, stream>>>(counts, rowptr, bsums, N);
    scanB<<<1, SCAN_B, 0, stream>>>(bsums, nb);
    scanC<<<gN, 256, 0, stream>>>(rowptr, bsums, counts, cursor, dinv, N);
    xcd_scatter<<<8 * 160, 256, 0, stream>>>(src, dst, cursor, ssorted, E, slice);

    // --- layer 1 ---
    gemm_tiled<128><<<(N + 63) / 64, 256, 0, stream>>>(x, Wa1, dinv, bufH, N);
    agg_csr<<<(N + 3) / 4, 256, 0, stream>>>(rowptr, cursor, ssorted, dinv, bufH, ba1, bufA, N);

    // --- layer 2 ---
    gemm_tiled<64><<<(N + 63) / 64, 256, 0, stream>>>(bufA, Wa2, dinv, bufH, N);
    agg_csr<<<(N + 3) / 4, 256, 0, stream>>>(rowptr, cursor, ssorted, dinv, bufH, ba2, bufA, N);

    // --- readout ---
    hipMemsetAsync(h64, 0, 4096 * sizeof(float), stream);
    outer_reduce<<<512, 256, 0, stream>>>(bufA, h64, N);
    final_kernel<<<1, 256, 0, stream>>>(h64, Wl, bl, out);
}

// Round 9
// 547.927 us; speedup vs baseline: 1.3543x; 1.3543x over previous
//
#include <hip/hip_runtime.h>

// ---------------------------------------------------------------------------
// PiNet: 2x GCNConv + a2^T a2 readout + linear + softmax
// N=100000, E=3200000, D0=128, D1=D2=64, OUT=10
// R8: atomic-free CSR build (block-local radix partition by dst>>8):
//     per-block LDS histograms -> two-level scan -> deterministic placement
//     with LDS-only atomics. Replaces hist_dst + xcd_scatter (R7: 141us,
//     130MB writes, global-atomic-bound). gemm keeps dinv-prescale epilogue.
// ---------------------------------------------------------------------------

#define CHUNK 4096   // edges per partition block
#define BSH   8      // bucket = dst >> 8 (256 nodes/bucket)

// Pass A: per-block bucket histogram (LDS atomics only).
__global__ __launch_bounds__(256) void hist_pass(const int* __restrict__ dst,
                                                 int* __restrict__ ghist,
                                                 int E, int nblk, int nbuck) {
    __shared__ int lcnt[512];
    const int blk = blockIdx.x;
    for (int i = threadIdx.x; i < nbuck; i += 256) lcnt[i] = 0;
    __syncthreads();
    const int base = blk * CHUNK;
    const int end  = min(base + CHUNK, E);
    for (int e = base + threadIdx.x; e < end; e += 256) {
        int d = __builtin_nontemporal_load(&dst[e]);
        atomicAdd(&lcnt[d >> BSH], 1);
    }
    __syncthreads();
    for (int b = threadIdx.x; b < nbuck; b += 256)
        ghist[(size_t)b * nblk + blk] = lcnt[b];
}

// Pass S1: per-bucket exclusive scan over blocks (in place) + bucket total.
__global__ __launch_bounds__(256) void scan_blocks(int* __restrict__ ghist,
                                                   int* __restrict__ btot, int nblk) {
    __shared__ int sh[256];
    int* g = ghist + (size_t)blockIdx.x * nblk;
    const int tid = threadIdx.x;
    int carry = 0;
    for (int base = 0; base < nblk; base += 256) {
        int i = base + tid;
        int v = (i < nblk) ? g[i] : 0;
        sh[tid] = v;
        __syncthreads();
        for (int off = 1; off < 256; off <<= 1) {
            int t = (tid >= off) ? sh[tid - off] : 0;
            __syncthreads();
            sh[tid] += t;
            __syncthreads();
        }
        if (i < nblk) g[i] = carry + sh[tid] - v;  // exclusive + carry
        int tot = sh[255];
        __syncthreads();
        carry += tot;
    }
    if (tid == 0) btot[blockIdx.x] = carry;
}

// Pass S2: exclusive scan of bucket totals -> bstart. nbuck <= 512.
__global__ void scan_bstart(const int* __restrict__ btot, int* __restrict__ bstart, int nb) {
    __shared__ int sh[512];
    const int tid = threadIdx.x;
    int v = (tid < nb) ? btot[tid] : 0;
    sh[tid] = v;
    __syncthreads();
    for (int off = 1; off < 512; off <<= 1) {
        int t = (tid >= off) ? sh[tid - off] : 0;
        __syncthreads();
        sh[tid] += t;
        __syncthreads();
    }
    if (tid < nb) bstart[tid] = sh[tid] - v;
}

// Pass B: place edges into bucket-contiguous bedges (LDS atomics only;
// each block owns a deterministic [bstart[b]+prefix, ...) run per bucket).
__global__ __launch_bounds__(256) void place_pass(const int* __restrict__ src,
                                                  const int* __restrict__ dst,
                                                  const int* __restrict__ ghist,
                                                  const int* __restrict__ bstart,
                                                  uint2* __restrict__ bedges,
                                                  int E, int nblk, int nbuck) {
    __shared__ int off[512];
    const int blk = blockIdx.x;
    for (int b = threadIdx.x; b < nbuck; b += 256)
        off[b] = bstart[b] + ghist[(size_t)b * nblk + blk];
    __syncthreads();
    const int base = blk * CHUNK;
    const int end  = min(base + CHUNK, E);
    for (int e = base + threadIdx.x; e < end; e += 256) {
        int d = __builtin_nontemporal_load(&dst[e]);
        int s = __builtin_nontemporal_load(&src[e]);
        int pos = atomicAdd(&off[d >> BSH], 1);
        bedges[pos] = make_uint2((unsigned)s, (unsigned)(d & 255));
    }
}

// Pass C: per-bucket counting sort -> ssorted + rowptr/rowend/dinv.
__global__ __launch_bounds__(256) void bucket_csr(const uint2* __restrict__ bedges,
                                                  const int* __restrict__ btot,
                                                  const int* __restrict__ bstart,
                                                  float* __restrict__ dinv,
                                                  int* __restrict__ rowptr,
                                                  int* __restrict__ rowend,
                                                  int* __restrict__ ssorted, int N) {
    __shared__ int lcnt[256];
    __shared__ int sc[256];
    __shared__ int lcur[256];
    const int b   = blockIdx.x;
    const int tid = threadIdx.x;
    const int cnt  = btot[b];
    const int base = bstart[b];
    lcnt[tid] = 0;
    __syncthreads();
    for (int i = tid; i < cnt; i += 256)
        atomicAdd(&lcnt[(int)bedges[base + i].y], 1);
    __syncthreads();
    int c = lcnt[tid];
    sc[tid] = c;
    __syncthreads();
    for (int off = 1; off < 256; off <<= 1) {
        int t = (tid >= off) ? sc[tid - off] : 0;
        __syncthreads();
        sc[tid] += t;
        __syncthreads();
    }
    const int excl = sc[tid] - c;
    const int n = (b << BSH) + tid;
    if (n < N) {
        dinv[n]   = rsqrtf((float)c + 1.0f);  // +1 self-loop
        rowptr[n] = base + excl;
        rowend[n] = base + excl + c;
    }
    lcur[tid] = excl;
    __syncthreads();
    for (int i = tid; i < cnt; i += 256) {
        uint2 e = bedges[base + i];
        int pos = atomicAdd(&lcur[(int)e.y], 1);
        ssorted[base + pos] = (int)e.x;
    }
}

// ---------------------------------------------------------------------------
// Register-tiled GEMM with dinv epilogue: H[n][c] = dinv[n] * sum_k A[n][k]*W[k][c]
// ---------------------------------------------------------------------------
template <int K>
__global__ __launch_bounds__(256) void gemm_tiled(const float* __restrict__ A,
                                                  const float* __restrict__ W,
                                                  const float* __restrict__ dinv,
                                                  float* __restrict__ H, int N) {
    constexpr int KC = 32;
    __shared__ float xs[64][KC + 4];
    __shared__ float ws[KC][64];
    const int tid  = threadIdx.x;
    const int tx   = tid & 15;
    const int ty   = tid >> 4;
    const int base = blockIdx.x * 64;

    float acc[4][4] = {{0.f}};

    for (int kc = 0; kc < K; kc += KC) {
        for (int idx = tid; idx < 512; idx += 256) {
            int node = idx >> 3, k4 = idx & 7;
            int n = base + node;
            float4 v = make_float4(0.f, 0.f, 0.f, 0.f);
            if (n < N) v = *(const float4*)&A[(long long)n * K + kc + k4 * 4];
            *(float4*)&xs[node][k4 * 4] = v;
        }
        for (int idx = tid; idx < 512; idx += 256) {
            int k = idx >> 4, c4 = idx & 15;
            *(float4*)&ws[k][c4 * 4] = *(const float4*)&W[(long long)(kc + k) * 64 + c4 * 4];
        }
        __syncthreads();

#pragma unroll
        for (int k = 0; k < KC; k += 4) {
            float4 xv[4], wv[4];
#pragma unroll
            for (int i = 0; i < 4; ++i) xv[i] = *(const float4*)&xs[ty * 4 + i][k];
#pragma unroll
            for (int j = 0; j < 4; ++j) wv[j] = *(const float4*)&ws[k + j][tx * 4];
#pragma unroll
            for (int i = 0; i < 4; ++i) {
                float xi[4] = {xv[i].x, xv[i].y, xv[i].z, xv[i].w};
#pragma unroll
                for (int j = 0; j < 4; ++j) {
                    acc[i][0] += xi[j] * wv[j].x;
                    acc[i][1] += xi[j] * wv[j].y;
                    acc[i][2] += xi[j] * wv[j].z;
                    acc[i][3] += xi[j] * wv[j].w;
                }
            }
        }
        __syncthreads();
    }

#pragma unroll
    for (int i = 0; i < 4; ++i) {
        int n = base + ty * 4 + i;
        if (n < N) {
            float d = dinv[n];
            float4 r = make_float4(d * acc[i][0], d * acc[i][1], d * acc[i][2], d * acc[i][3]);
            *(float4*)&H[(long long)n * 64 + tx * 4] = r;
        }
    }
}

// CSR aggregation, fused bias + self-loop. One wave per node.
// H is pre-scaled by dinv: out[n] = bias + dinv[n] * (H[n] + sum_s H[s]).
__global__ void agg_csr(const int* __restrict__ rowptr, const int* __restrict__ endptr,
                        const int* __restrict__ ssorted, const float* __restrict__ dinv,
                        const float* __restrict__ H, const float* __restrict__ bias,
                        float* __restrict__ out, int N) {
    const int wid  = (int)(((long long)blockIdx.x * blockDim.x + threadIdx.x) >> 6);
    if (wid >= N) return;
    const int lane = threadIdx.x & 63;
    const int g    = lane >> 4;
    const int fl   = lane & 15;
    const float4* __restrict__ Hv = (const float4*)H;

    const int   n   = wid;
    const int   beg = rowptr[n];
    const int   end = endptr[n];

    float4 acc = make_float4(0.f, 0.f, 0.f, 0.f);
    for (int e = beg + g; e < end; e += 4) {
        int    s  = ssorted[e];
        float4 hv = Hv[(long long)s * 16 + fl];
        acc.x += hv.x; acc.y += hv.y; acc.z += hv.z; acc.w += hv.w;
    }
    acc.x += __shfl_xor(acc.x, 16); acc.y += __shfl_xor(acc.y, 16);
    acc.z += __shfl_xor(acc.z, 16); acc.w += __shfl_xor(acc.w, 16);
    acc.x += __shfl_xor(acc.x, 32); acc.y += __shfl_xor(acc.y, 32);
    acc.z += __shfl_xor(acc.z, 32); acc.w += __shfl_xor(acc.w, 32);

    if (g == 0) {
        float4 selfv = Hv[(long long)n * 16 + fl];
        float4 bv    = ((const float4*)bias)[fl];
        float  dn    = dinv[n];
        float4 res;
        res.x = bv.x + dn * (selfv.x + acc.x);
        res.y = bv.y + dn * (selfv.y + acc.y);
        res.z = bv.z + dn * (selfv.z + acc.z);
        res.w = bv.w + dn * (selfv.w + acc.w);
        ((float4*)out)[(long long)n * 16 + fl] = res;
    }
}

// h64[r][c] += sum_n A2[n][r] * A2[n][c]
__global__ void outer_reduce(const float* __restrict__ A2, float* __restrict__ h64, int N) {
    __shared__ float rows[8][64];
    const int tid = threadIdx.x;
    const int col = tid & 63;
    const int rg  = tid >> 6;
    float acc[16];
#pragma unroll
    for (int i = 0; i < 16; ++i) acc[i] = 0.f;

    int npb   = (N + gridDim.x - 1) / gridDim.x;
    int start = blockIdx.x * npb;
    int end   = min(start + npb, N);
    for (int nb = start; nb < end; nb += 8) {
        int cnt = min(8, end - nb);
        __syncthreads();
        for (int idx = tid; idx < cnt * 64; idx += 256)
            rows[idx >> 6][idx & 63] = A2[(long long)(nb + (idx >> 6)) * 64 + (idx & 63)];
        __syncthreads();
        for (int r = 0; r < cnt; ++r) {
            float vc = rows[r][col];
#pragma unroll
            for (int i = 0; i < 16; ++i)
                acc[i] += rows[r][rg * 16 + i] * vc;
        }
    }
#pragma unroll
    for (int i = 0; i < 16; ++i)
        atomicAdd(&h64[(rg * 16 + i) * 64 + col], acc[i]);
}

// o = h64.flat @ Wl + bl ; softmax -> out[10]
__global__ void final_kernel(const float* __restrict__ h64, const float* __restrict__ Wl,
                             const float* __restrict__ bl, float* __restrict__ out) {
    __shared__ float red[256];
    __shared__ float o[10];
    const int tid = threadIdx.x;
    float acc[10];
#pragma unroll
    for (int k = 0; k < 10; ++k) acc[k] = 0.f;
    for (int i = tid; i < 4096; i += 256) {
        float v = h64[i];
#pragma unroll
        for (int k = 0; k < 10; ++k) acc[k] += v * Wl[i * 10 + k];
    }
    for (int k = 0; k < 10; ++k) {
        red[tid] = acc[k];
        __syncthreads();
        for (int s = 128; s > 0; s >>= 1) {
            if (tid < s) red[tid] += red[tid + s];
            __syncthreads();
        }
        if (tid == 0) o[k] = red[0] + bl[k];
        __syncthreads();
    }
    if (tid == 0) {
        float m = o[0];
        for (int k = 1; k < 10; ++k) m = fmaxf(m, o[k]);
        float s = 0.f, e[10];
        for (int k = 0; k < 10; ++k) { e[k] = expf(o[k] - m); s += e[k]; }
        for (int k = 0; k < 10; ++k) out[k] = e[k] / s;
    }
}

extern "C" void kernel_launch(void* const* d_in, const int* in_sizes, int n_in,
                              void* d_out, int out_size, void* d_ws, size_t ws_size,
                              hipStream_t stream) {
    const float* x   = (const float*)d_in[0];
    const int*   ei  = (const int*)d_in[1];
    const float* Wa1 = (const float*)d_in[2];
    const float* ba1 = (const float*)d_in[3];
    const float* Wa2 = (const float*)d_in[4];
    const float* ba2 = (const float*)d_in[5];
    const float* Wl  = (const float*)d_in[6];
    const float* bl  = (const float*)d_in[7];
    float* out = (float*)d_out;

    const int N = in_sizes[0] / 128;
    const int E = in_sizes[1] / 2;
    const int* src = ei;
    const int* dst = ei + E;

    const int nblk  = (E + CHUNK - 1) / CHUNK;   // 782
    const int nbuck = (N + 255) >> BSH;          // 391 (<= 512)

    // --- workspace layout ---
    // region0 (union, 51.2MB): bufH+bufA  |  bedges(25.6MB)+ghist(1.25MB)+btot+bstart
    char* wsb = (char*)d_ws;
    float* bufH   = (float*)wsb;
    float* bufA   = bufH + (size_t)N * 64;
    uint2* bedges = (uint2*)wsb;                           // [E]
    int*   ghist  = (int*)(wsb + (size_t)E * 8);           // [nbuck*nblk]
    int*   btot   = ghist + (size_t)nbuck * nblk;          // [512]
    int*   bstart = btot + 512;                            // [512]
    char*  tail   = wsb + (size_t)N * 128 * 4;             // 51.2MB
    float* dinv   = (float*)tail;               tail += (size_t)N * 4;
    float* h64    = (float*)tail;               tail += 4096 * 4;
    int*   rowptr = (int*)tail;                 tail += (size_t)N * 4;
    int*   rowend = (int*)tail;                 tail += (size_t)N * 4;
    int*   ssorted= (int*)tail;                 tail += (size_t)E * 4;

    // --- CSR build (no global atomics) ---
    hist_pass<<<nblk, 256, 0, stream>>>(dst, ghist, E, nblk, nbuck);
    scan_blocks<<<nbuck, 256, 0, stream>>>(ghist, btot, nblk);
    scan_bstart<<<1, 512, 0, stream>>>(btot, bstart, nbuck);
    place_pass<<<nblk, 256, 0, stream>>>(src, dst, ghist, bstart, bedges, E, nblk, nbuck);
    bucket_csr<<<nbuck, 256, 0, stream>>>(bedges, btot, bstart, dinv, rowptr, rowend, ssorted, N);

    // --- layer 1 ---
    gemm_tiled<128><<<(N + 63) / 64, 256, 0, stream>>>(x, Wa1, dinv, bufH, N);
    agg_csr<<<(N + 3) / 4, 256, 0, stream>>>(rowptr, rowend, ssorted, dinv, bufH, ba1, bufA, N);

    // --- layer 2 ---
    gemm_tiled<64><<<(N + 63) / 64, 256, 0, stream>>>(bufA, Wa2, dinv, bufH, N);
    agg_csr<<<(N + 3) / 4, 256, 0, stream>>>(rowptr, rowend, ssorted, dinv, bufH, ba2, bufA, N);

    // --- readout ---
    hipMemsetAsync(h64, 0, 4096 * sizeof(float), stream);
    outer_reduce<<<512, 256, 0, stream>>>(bufA, h64, N);
    final_kernel<<<1, 256, 0, stream>>>(h64, Wl, bl, out);
}